// Round 9
// baseline (498.942 us; speedup 1.0000x reference)
//
#include <hip/hip_runtime.h>
#include <stdint.h>

#define ED   768
#define NH   12
#define HD   64
#define SEQ  4096
#define BSZ  2
#define BHT  (BSZ*NH)          // 24
#define MTOT (BSZ*SEQ)         // 8192

typedef short bf16x8  __attribute__((ext_vector_type(8)));   // 8 bf16 (4 VGPRs)
typedef float f32x4   __attribute__((ext_vector_type(4)));
typedef float f32x16  __attribute__((ext_vector_type(16)));

#define LOG2E 1.44269504088896340736f
#define C2    (0.125f * LOG2E)   // folded into Q at projection time

// fp32 -> bf16 round-to-nearest-even
__device__ __forceinline__ unsigned short f2bf(float f) {
    union { float f; uint32_t u; } v; v.f = f;
    uint32_t u = v.u;
    u += 0x7fffu + ((u >> 16) & 1u);
    return (unsigned short)(u >> 16);
}

// pack two fp32 -> one u32 of two bf16 (RNE).  HW cvt if available.
#if defined(__has_builtin)
#if __has_builtin(__builtin_amdgcn_cvt_pk_bf16_f32)
#define HAVE_CVT_PK_BF16 1
#endif
#endif
__device__ __forceinline__ uint32_t pkbf16(float a, float b) {
#ifdef HAVE_CVT_PK_BF16
    typedef __bf16 bf16x2_t __attribute__((ext_vector_type(2)));
    union { bf16x2_t v; uint32_t u; } c;
    c.v = __builtin_amdgcn_cvt_pk_bf16_f32(a, b);
    return c.u;
#else
    union { float f; uint32_t u; } x, y; x.f = a; y.f = b;
    return __builtin_amdgcn_perm(y.u + 0x8000u, x.u + 0x8000u, 0x07060302u);
#endif
}

// async global->LDS, 16B/lane; lds dst = wave-uniform base, lands at base+lane*16
__device__ __forceinline__ void cp16(const unsigned short* g, unsigned short* l) {
    __builtin_amdgcn_global_load_lds(
        (const __attribute__((address_space(1))) unsigned int*)(const void*)g,
        (__attribute__((address_space(3))) unsigned int*)(void*)l,
        16, 0, 0);
}
// XOR-swizzle (GEMMs): LDS 16B-chunk slot c of row r holds global chunk c^(r&7).

// ---------------------------------------------------------------------------
// Kernel 0: one-time fp32->bf16 convert. H,Wq|Wk|Wv -> d_out scratch (dead
// until out_gemm writes); Wo -> WoB in d_ws; mask -> bf16(LOG2E*mask) in d_ws.
// ---------------------------------------------------------------------------
#define H_CHUNKS  (MTOT * ED / 4)            // 1572864 float4s
#define W_CHUNKS  (ED * ED / 4)              // 147456 per weight
#define MB_CHUNKS (BSZ * SEQ / 4)            // 2048
#define CVT_TOTAL (H_CHUNKS + 4 * W_CHUNKS + MB_CHUNKS)  // 2164736 = 8456*256

__global__ __launch_bounds__(256) void convert_bf16(
    const float* __restrict__ H,  const float* __restrict__ Wq,
    const float* __restrict__ Wk, const float* __restrict__ Wv,
    const float* __restrict__ Wo, const float* __restrict__ Mask,
    unsigned short* __restrict__ dst, unsigned short* __restrict__ WoB,
    unsigned short* __restrict__ maskB) {
    int i4 = blockIdx.x * 256 + threadIdx.x;
    float4 v;
    ushort4* optr;
    if (i4 < H_CHUNKS) { v = ((const float4*)H)[i4]; optr = (ushort4*)dst + i4; }
    else {
        int j = i4 - H_CHUNKS;
        if (j < 3 * W_CHUNKS) {
            if (j < W_CHUNKS)          v = ((const float4*)Wq)[j];
            else if (j < 2 * W_CHUNKS) v = ((const float4*)Wk)[j - W_CHUNKS];
            else                       v = ((const float4*)Wv)[j - 2 * W_CHUNKS];
            optr = (ushort4*)dst + i4;
        } else if (j < 4 * W_CHUNKS) {
            v = ((const float4*)Wo)[j - 3 * W_CHUNKS];
            optr = (ushort4*)WoB + (j - 3 * W_CHUNKS);
        } else {
            int m = j - 4 * W_CHUNKS;
            float4 mv = ((const float4*)Mask)[m];
            ushort4 o;
            o.x = f2bf(LOG2E * mv.x); o.y = f2bf(LOG2E * mv.y);
            o.z = f2bf(LOG2E * mv.z); o.w = f2bf(LOG2E * mv.w);
            ((ushort4*)maskB)[m] = o;
            return;
        }
    }
    ushort4 o;
    o.x = f2bf(v.x); o.y = f2bf(v.y); o.z = f2bf(v.z); o.w = f2bf(v.w);
    *optr = o;
}

// ---------------------------------------------------------------------------
// Kernel 1: QKV projection, 128x128 tile, BK=64, global_load_lds + XOR swizzle.
// Q written pre-scaled by C2.  Q,K -> [b][h][s][d];  V -> [b][h][d][s].
// ---------------------------------------------------------------------------
__global__ __launch_bounds__(256) void qkv_gemm(
    const unsigned short* __restrict__ Hb,   // [8192][768] bf16
    const unsigned short* __restrict__ Wb,   // [2304][768] bf16 (Wq|Wk|Wv)
    unsigned short* __restrict__ qkv) {
    __shared__ __align__(16) unsigned short Ah[128 * 64];
    __shared__ __align__(16) unsigned short Bh[128 * 64];
    const int t = threadIdx.x, w = t >> 6, lane = t & 63;
    const int quad = lane >> 4, r16 = lane & 15;
    const int wm = w >> 1, wn = w & 1;
    const int m0 = blockIdx.y * 128, n0g = blockIdx.x * 128;
    const int wsel = n0g / ED, n0 = n0g % ED;
    const int lrow = lane >> 3;
    const int lchs = ((lane & 7) ^ (lrow & 7)) * 8;

    f32x4 acc[4][4] = {};
    for (int kt = 0; kt < ED / 64; ++kt) {
        const int k0 = kt * 64;
#pragma unroll
        for (int i = 0; i < 4; ++i) {
            int row = i * 32 + w * 8;
            cp16(&Hb[(size_t)(m0 + row + lrow) * ED + k0 + lchs], &Ah[row * 64]);
            cp16(&Wb[(size_t)(n0g + row + lrow) * ED + k0 + lchs], &Bh[row * 64]);
        }
        __syncthreads();
#pragma unroll
        for (int kk = 0; kk < 2; ++kk) {
            bf16x8 aF[4], bF[4];
#pragma unroll
            for (int mi = 0; mi < 4; ++mi) {
                int R = wm * 64 + mi * 16 + r16;
                aF[mi] = *(const bf16x8*)&Ah[R * 64 + (((kk * 4 + quad) ^ (r16 & 7)) * 8)];
            }
#pragma unroll
            for (int ni = 0; ni < 4; ++ni) {
                int R = wn * 64 + ni * 16 + r16;
                bF[ni] = *(const bf16x8*)&Bh[R * 64 + (((kk * 4 + quad) ^ (r16 & 7)) * 8)];
            }
            if (wsel == 2) {
#pragma unroll
                for (int mi = 0; mi < 4; ++mi)
#pragma unroll
                    for (int ni = 0; ni < 4; ++ni)
                        acc[mi][ni] = __builtin_amdgcn_mfma_f32_16x16x32_bf16(
                            bF[ni], aF[mi], acc[mi][ni], 0, 0, 0);
            } else {
#pragma unroll
                for (int mi = 0; mi < 4; ++mi)
#pragma unroll
                    for (int ni = 0; ni < 4; ++ni)
                        acc[mi][ni] = __builtin_amdgcn_mfma_f32_16x16x32_bf16(
                            aF[mi], bF[ni], acc[mi][ni], 0, 0, 0);
            }
        }
        __syncthreads();
    }
    const size_t WSZ = (size_t)BHT * SEQ * HD;
    if (wsel == 2) {
#pragma unroll
        for (int mi = 0; mi < 4; ++mi)
#pragma unroll
            for (int ni = 0; ni < 4; ++ni)
#pragma unroll
                for (int r = 0; r < 4; ++r) {
                    int m  = m0 + wm * 64 + mi * 16 + r16;
                    int nn = n0 + wn * 64 + ni * 16 + quad * 4 + r;
                    int b = m >> 12, s = m & 4095;
                    int hh = nn >> 6, dd = nn & 63;
                    qkv[2 * WSZ + (((size_t)b * NH + hh) * HD + dd) * SEQ + s] =
                        f2bf(acc[mi][ni][r]);
                }
    } else {
        const float sc = (wsel == 0) ? C2 : 1.0f;
#pragma unroll
        for (int mi = 0; mi < 4; ++mi)
#pragma unroll
            for (int ni = 0; ni < 4; ++ni)
#pragma unroll
                for (int r = 0; r < 4; ++r) {
                    int m = m0 + wm * 64 + mi * 16 + quad * 4 + r;
                    int b = m >> 12, s = m & 4095;
                    int nn = n0 + wn * 64 + ni * 16 + r16;
                    int hh = nn >> 6, dd = nn & 63;
                    size_t off = (((size_t)b * NH + hh) * SEQ + s) * HD + dd;
                    qkv[(size_t)wsel * WSZ + off] = f2bf(acc[mi][ni][r] * sc);
                }
    }
}

// ---------------------------------------------------------------------------
// Kernel 2: flash attention — BARRIER-FREE.  4 waves x 32 q; K and V^T
// fragments are contiguous 16B global loads (L2/L3-served), so no LDS staging
// and no __syncthreads at all.  Only LDS use: per-wave Psm C->A round trip.
// Fixed-max softmax (log2 domain, Q pre-scaled by C2, mask pre-scaled LOG2E).
// ---------------------------------------------------------------------------
__global__ __launch_bounds__(256) void flash_attn(
    const unsigned short* __restrict__ qkv,
    const unsigned short* __restrict__ maskB,   // bf16(LOG2E*mask) [b][key]
    unsigned short* __restrict__ ctx) {
    __shared__ __align__(16) unsigned short Psm[4][32][72]; // per-wave [q][key]
    const int t  = threadIdx.x;
    const int bh = blockIdx.y;
    const int b  = bh / NH;
    const int h  = bh % NH;
    const int qbase = blockIdx.x * 128;
    const size_t WSZ = (size_t)BHT * SEQ * HD;
    const unsigned short* Qp = qkv + (size_t)bh * SEQ * HD;
    const unsigned short* Kp = Qp + WSZ;
    const unsigned short* Vt = qkv + 2 * WSZ + (size_t)bh * HD * SEQ; // [d][s]
    const unsigned short* mrow = maskB + b * SEQ;
    const int w = t >> 6, lane = t & 63, n31 = lane & 31, hi = lane >> 5;

    bf16x8 qF[4];
    {
        int qrow = qbase + w * 32 + n31;
#pragma unroll
        for (int kc = 0; kc < 4; ++kc)
            qF[kc] = *(const bf16x8*)&Qp[(size_t)qrow * HD + kc * 16 + hi * 8];
    }
    bf16x8 bOnes = {};
    if (hi == 0) bOnes[0] = (short)0x3F80;   // 1.0 at k==0 (mask broadcast)
    const f32x16 kZero = {};

    f32x16 oAcc[2] = {};
    float l_i = 0.0f;

    for (int kt = 0; kt < SEQ / 64; ++kt) {
        const unsigned short* Kt = Kp + (size_t)kt * 64 * HD;
        const unsigned short* Vk = Vt + kt * 64;

        // S^T = K Q^T (log2 domain) + mask via MFMA C-init; exp2; pack -> Psm
#pragma unroll
        for (int st = 0; st < 2; ++st) {
            bf16x8 am = {};
            {
                unsigned short mv = mrow[kt * 64 + st * 32 + n31];
                am[0] = (hi == 0) ? (short)mv : (short)0;
            }
            f32x16 sA = __builtin_amdgcn_mfma_f32_32x32x16_bf16(am, bOnes, kZero, 0, 0, 0);
#pragma unroll
            for (int kc = 0; kc < 4; ++kc) {
                bf16x8 kF = *(const bf16x8*)
                    &Kt[(size_t)(st * 32 + n31) * HD + kc * 16 + hi * 8];
                sA = __builtin_amdgcn_mfma_f32_32x32x16_bf16(kF, qF[kc], sA, 0, 0, 0);
            }
            float r0 = 0.f, r1 = 0.f, r2 = 0.f, r3 = 0.f;
#pragma unroll
            for (int g = 0; g < 4; ++g) {
                float p0 = __builtin_amdgcn_exp2f(sA[4 * g + 0]);
                float p1 = __builtin_amdgcn_exp2f(sA[4 * g + 1]);
                float p2 = __builtin_amdgcn_exp2f(sA[4 * g + 2]);
                float p3 = __builtin_amdgcn_exp2f(sA[4 * g + 3]);
                r0 += p0; r1 += p1; r2 += p2; r3 += p3;
                uint2 dd;
                dd.x = pkbf16(p0, p1);
                dd.y = pkbf16(p2, p3);
                *(uint2*)&Psm[w][n31][st * 32 + hi * 4 + 8 * g] = dd;
            }
            l_i += (r0 + r1) + (r2 + r3);
        }

        // O^T += V^T P^T  (vF direct from global: contiguous 16B in key dim)
#pragma unroll
        for (int kc = 0; kc < 4; ++kc) {
            bf16x8 pF = *(const bf16x8*)&Psm[w][n31][kc * 16 + hi * 8];
#pragma unroll
            for (int dt = 0; dt < 2; ++dt) {
                bf16x8 vF = *(const bf16x8*)
                    &Vk[(size_t)(dt * 32 + n31) * SEQ + kc * 16 + hi * 8];
                oAcc[dt] = __builtin_amdgcn_mfma_f32_32x32x16_bf16(vF, pF, oAcc[dt], 0, 0, 0);
            }
        }
    }
    // epilogue: lane covers half the keys; partner (lane^32) has the other half
    l_i += __shfl_xor(l_i, 32);
    float inv = 1.0f / l_i;
    int s = qbase + w * 32 + n31;
    unsigned short* obase = &ctx[((size_t)b * SEQ + s) * ED + h * HD];
#pragma unroll
    for (int dt = 0; dt < 2; ++dt)
#pragma unroll
        for (int g = 0; g < 4; ++g) {
            uint2 o;
            o.x = pkbf16(oAcc[dt][4 * g + 0] * inv, oAcc[dt][4 * g + 1] * inv);
            o.y = pkbf16(oAcc[dt][4 * g + 2] * inv, oAcc[dt][4 * g + 3] * inv);
            *(uint2*)&obase[dt * 32 + hi * 4 + 8 * g] = o;
        }
}

// ---------------------------------------------------------------------------
// Kernel 3: output projection, 128x128 tile.
// ---------------------------------------------------------------------------
__global__ __launch_bounds__(256) void out_gemm(
    const unsigned short* __restrict__ Ab,   // ctx bf16 [8192][768]
    const unsigned short* __restrict__ Wob,  // [768][768] bf16
    const float* __restrict__ bo, float* __restrict__ out) {
    __shared__ __align__(16) unsigned short Ah[128 * 64];
    __shared__ __align__(16) unsigned short Bh[128 * 64];
    const int t = threadIdx.x, w = t >> 6, lane = t & 63;
    const int quad = lane >> 4, r16 = lane & 15;
    const int wm = w >> 1, wn = w & 1;
    const int m0 = blockIdx.y * 128, n0 = blockIdx.x * 128;
    const int lrow = lane >> 3;
    const int lchs = ((lane & 7) ^ (lrow & 7)) * 8;

    f32x4 acc[4][4] = {};
    for (int kt = 0; kt < ED / 64; ++kt) {
        const int k0 = kt * 64;
#pragma unroll
        for (int i = 0; i < 4; ++i) {
            int row = i * 32 + w * 8;
            cp16(&Ab[(size_t)(m0 + row + lrow) * ED + k0 + lchs], &Ah[row * 64]);
            cp16(&Wob[(size_t)(n0 + row + lrow) * ED + k0 + lchs], &Bh[row * 64]);
        }
        __syncthreads();
#pragma unroll
        for (int kk = 0; kk < 2; ++kk) {
            bf16x8 aF[4], bF[4];
#pragma unroll
            for (int mi = 0; mi < 4; ++mi) {
                int R = wm * 64 + mi * 16 + r16;
                aF[mi] = *(const bf16x8*)&Ah[R * 64 + (((kk * 4 + quad) ^ (r16 & 7)) * 8)];
            }
#pragma unroll
            for (int ni = 0; ni < 4; ++ni) {
                int R = wn * 64 + ni * 16 + r16;
                bF[ni] = *(const bf16x8*)&Bh[R * 64 + (((kk * 4 + quad) ^ (r16 & 7)) * 8)];
            }
#pragma unroll
            for (int mi = 0; mi < 4; ++mi)
#pragma unroll
                for (int ni = 0; ni < 4; ++ni)
                    acc[mi][ni] = __builtin_amdgcn_mfma_f32_16x16x32_bf16(
                        aF[mi], bF[ni], acc[mi][ni], 0, 0, 0);
        }
        __syncthreads();
    }
    float bov[4];
#pragma unroll
    for (int ni = 0; ni < 4; ++ni) bov[ni] = bo[n0 + wn * 64 + ni * 16 + r16];
#pragma unroll
    for (int mi = 0; mi < 4; ++mi)
#pragma unroll
        for (int ni = 0; ni < 4; ++ni)
#pragma unroll
            for (int r = 0; r < 4; ++r) {
                int m = m0 + wm * 64 + mi * 16 + quad * 4 + r;
                int n = n0 + wn * 64 + ni * 16 + r16;
                out[(size_t)m * ED + n] = acc[mi][ni][r] + bov[ni];
            }
}

// ---------------------------------------------------------------------------
extern "C" void kernel_launch(void* const* d_in, const int* in_sizes, int n_in,
                              void* d_out, int out_size, void* d_ws, size_t ws_size,
                              hipStream_t stream) {
    const float* H    = (const float*)d_in[0];
    const float* mask = (const float*)d_in[1];
    const float* Wq   = (const float*)d_in[2];
    const float* Wk   = (const float*)d_in[3];
    const float* Wv   = (const float*)d_in[4];
    const float* Wo   = (const float*)d_in[5];
    const float* bo   = (const float*)d_in[6];
    unsigned short* ws = (unsigned short*)d_ws;
    const size_t WSZ = (size_t)BHT * SEQ * HD;
    unsigned short* qkv   = ws;                           // 3*WSZ bf16
    unsigned short* ctx   = ws + 3 * WSZ;                 // [8192][768] bf16
    unsigned short* WoB   = ctx + (size_t)MTOT * ED;      // [768][768] bf16
    unsigned short* maskB = WoB + (size_t)ED * ED;        // [2][4096] bf16
    float* out = (float*)d_out;
    unsigned short* Hb = (unsigned short*)d_out;          // scratch until out_gemm
    unsigned short* Wb = Hb + (size_t)MTOT * ED;

    convert_bf16<<<CVT_TOTAL / 256, 256, 0, stream>>>(H, Wq, Wk, Wv, Wo, mask,
                                                      Hb, WoB, maskB);
    qkv_gemm<<<dim3(3 * ED / 128, MTOT / 128), 256, 0, stream>>>(Hb, Wb, qkv);
    flash_attn<<<dim3(SEQ / 128, BHT), 256, 0, stream>>>(qkv, maskB, ctx);
    out_gemm<<<dim3(ED / 128, MTOT / 128), 256, 0, stream>>>(ctx, WoB, bo, out);
}

// Round 10
// 310.012 us; speedup vs baseline: 1.6094x; 1.6094x over previous
//
#include <hip/hip_runtime.h>
#include <stdint.h>

#define ED   768
#define NH   12
#define HD   64
#define SEQ  4096
#define BSZ  2
#define BHT  (BSZ*NH)          // 24
#define MTOT (BSZ*SEQ)         // 8192

typedef short bf16x8  __attribute__((ext_vector_type(8)));   // 8 bf16 (4 VGPRs)
typedef float f32x4   __attribute__((ext_vector_type(4)));
typedef float f32x16  __attribute__((ext_vector_type(16)));

#define LOG2E 1.44269504088896340736f
#define C2    (0.125f * LOG2E)   // folded into Q at projection time

// fp32 -> bf16 round-to-nearest-even
__device__ __forceinline__ unsigned short f2bf(float f) {
    union { float f; uint32_t u; } v; v.f = f;
    uint32_t u = v.u;
    u += 0x7fffu + ((u >> 16) & 1u);
    return (unsigned short)(u >> 16);
}

// pack two fp32 -> one u32 of two bf16 (RNE).  HW cvt if available.
#if defined(__has_builtin)
#if __has_builtin(__builtin_amdgcn_cvt_pk_bf16_f32)
#define HAVE_CVT_PK_BF16 1
#endif
#endif
__device__ __forceinline__ uint32_t pkbf16(float a, float b) {
#ifdef HAVE_CVT_PK_BF16
    typedef __bf16 bf16x2_t __attribute__((ext_vector_type(2)));
    union { bf16x2_t v; uint32_t u; } c;
    c.v = __builtin_amdgcn_cvt_pk_bf16_f32(a, b);
    return c.u;
#else
    union { float f; uint32_t u; } x, y; x.f = a; y.f = b;
    return __builtin_amdgcn_perm(y.u + 0x8000u, x.u + 0x8000u, 0x07060302u);
#endif
}

// async global->LDS, 16B/lane; lds dst = wave-uniform base, lands at base+lane*16
__device__ __forceinline__ void cp16(const unsigned short* g, unsigned short* l) {
    __builtin_amdgcn_global_load_lds(
        (const __attribute__((address_space(1))) unsigned int*)(const void*)g,
        (__attribute__((address_space(3))) unsigned int*)(void*)l,
        16, 0, 0);
}
// XOR-swizzle: LDS 16B-chunk slot c of row r holds global chunk c^(r&7).

// ---------------------------------------------------------------------------
// Kernel 0: one-time fp32->bf16 convert. H,Wq|Wk|Wv -> d_out scratch (dead
// until out_gemm writes); Wo -> WoB in d_ws; mask -> bf16(LOG2E*mask) in d_ws.
// ---------------------------------------------------------------------------
#define H_CHUNKS  (MTOT * ED / 4)            // 1572864 float4s
#define W_CHUNKS  (ED * ED / 4)              // 147456 per weight
#define MB_CHUNKS (BSZ * SEQ / 4)            // 2048
#define CVT_TOTAL (H_CHUNKS + 4 * W_CHUNKS + MB_CHUNKS)  // 2164736 = 8456*256

__global__ __launch_bounds__(256) void convert_bf16(
    const float* __restrict__ H,  const float* __restrict__ Wq,
    const float* __restrict__ Wk, const float* __restrict__ Wv,
    const float* __restrict__ Wo, const float* __restrict__ Mask,
    unsigned short* __restrict__ dst, unsigned short* __restrict__ WoB,
    unsigned short* __restrict__ maskB) {
    int i4 = blockIdx.x * 256 + threadIdx.x;
    float4 v;
    ushort4* optr;
    if (i4 < H_CHUNKS) { v = ((const float4*)H)[i4]; optr = (ushort4*)dst + i4; }
    else {
        int j = i4 - H_CHUNKS;
        if (j < 3 * W_CHUNKS) {
            if (j < W_CHUNKS)          v = ((const float4*)Wq)[j];
            else if (j < 2 * W_CHUNKS) v = ((const float4*)Wk)[j - W_CHUNKS];
            else                       v = ((const float4*)Wv)[j - 2 * W_CHUNKS];
            optr = (ushort4*)dst + i4;
        } else if (j < 4 * W_CHUNKS) {
            v = ((const float4*)Wo)[j - 3 * W_CHUNKS];
            optr = (ushort4*)WoB + (j - 3 * W_CHUNKS);
        } else {
            int m = j - 4 * W_CHUNKS;
            float4 mv = ((const float4*)Mask)[m];
            ushort4 o;
            o.x = f2bf(LOG2E * mv.x); o.y = f2bf(LOG2E * mv.y);
            o.z = f2bf(LOG2E * mv.z); o.w = f2bf(LOG2E * mv.w);
            ((ushort4*)maskB)[m] = o;
            return;
        }
    }
    ushort4 o;
    o.x = f2bf(v.x); o.y = f2bf(v.y); o.z = f2bf(v.z); o.w = f2bf(v.w);
    *optr = o;
}

// ---------------------------------------------------------------------------
// Kernel 1: QKV projection, 128x128 tile, BK=64, global_load_lds + XOR swizzle.
// Q written pre-scaled by C2.  Q,K -> [b][h][s][d];  V -> [b][h][d][s].
// ---------------------------------------------------------------------------
__global__ __launch_bounds__(256) void qkv_gemm(
    const unsigned short* __restrict__ Hb,   // [8192][768] bf16
    const unsigned short* __restrict__ Wb,   // [2304][768] bf16 (Wq|Wk|Wv)
    unsigned short* __restrict__ qkv) {
    __shared__ __align__(16) unsigned short Ah[128 * 64];
    __shared__ __align__(16) unsigned short Bh[128 * 64];
    const int t = threadIdx.x, w = t >> 6, lane = t & 63;
    const int quad = lane >> 4, r16 = lane & 15;
    const int wm = w >> 1, wn = w & 1;
    const int m0 = blockIdx.y * 128, n0g = blockIdx.x * 128;
    const int wsel = n0g / ED, n0 = n0g % ED;
    const int lrow = lane >> 3;
    const int lchs = ((lane & 7) ^ (lrow & 7)) * 8;

    f32x4 acc[4][4] = {};
    for (int kt = 0; kt < ED / 64; ++kt) {
        const int k0 = kt * 64;
#pragma unroll
        for (int i = 0; i < 4; ++i) {
            int row = i * 32 + w * 8;
            cp16(&Hb[(size_t)(m0 + row + lrow) * ED + k0 + lchs], &Ah[row * 64]);
            cp16(&Wb[(size_t)(n0g + row + lrow) * ED + k0 + lchs], &Bh[row * 64]);
        }
        __syncthreads();
#pragma unroll
        for (int kk = 0; kk < 2; ++kk) {
            bf16x8 aF[4], bF[4];
#pragma unroll
            for (int mi = 0; mi < 4; ++mi) {
                int R = wm * 64 + mi * 16 + r16;
                aF[mi] = *(const bf16x8*)&Ah[R * 64 + (((kk * 4 + quad) ^ (r16 & 7)) * 8)];
            }
#pragma unroll
            for (int ni = 0; ni < 4; ++ni) {
                int R = wn * 64 + ni * 16 + r16;
                bF[ni] = *(const bf16x8*)&Bh[R * 64 + (((kk * 4 + quad) ^ (r16 & 7)) * 8)];
            }
            if (wsel == 2) {
#pragma unroll
                for (int mi = 0; mi < 4; ++mi)
#pragma unroll
                    for (int ni = 0; ni < 4; ++ni)
                        acc[mi][ni] = __builtin_amdgcn_mfma_f32_16x16x32_bf16(
                            bF[ni], aF[mi], acc[mi][ni], 0, 0, 0);
            } else {
#pragma unroll
                for (int mi = 0; mi < 4; ++mi)
#pragma unroll
                    for (int ni = 0; ni < 4; ++ni)
                        acc[mi][ni] = __builtin_amdgcn_mfma_f32_16x16x32_bf16(
                            aF[mi], bF[ni], acc[mi][ni], 0, 0, 0);
            }
        }
        __syncthreads();
    }
    const size_t WSZ = (size_t)BHT * SEQ * HD;
    if (wsel == 2) {
#pragma unroll
        for (int mi = 0; mi < 4; ++mi)
#pragma unroll
            for (int ni = 0; ni < 4; ++ni)
#pragma unroll
                for (int r = 0; r < 4; ++r) {
                    int m  = m0 + wm * 64 + mi * 16 + r16;
                    int nn = n0 + wn * 64 + ni * 16 + quad * 4 + r;
                    int b = m >> 12, s = m & 4095;
                    int hh = nn >> 6, dd = nn & 63;
                    qkv[2 * WSZ + (((size_t)b * NH + hh) * HD + dd) * SEQ + s] =
                        f2bf(acc[mi][ni][r]);
                }
    } else {
        const float sc = (wsel == 0) ? C2 : 1.0f;
#pragma unroll
        for (int mi = 0; mi < 4; ++mi)
#pragma unroll
            for (int ni = 0; ni < 4; ++ni)
#pragma unroll
                for (int r = 0; r < 4; ++r) {
                    int m = m0 + wm * 64 + mi * 16 + quad * 4 + r;
                    int b = m >> 12, s = m & 4095;
                    int nn = n0 + wn * 64 + ni * 16 + r16;
                    int hh = nn >> 6, dd = nn & 63;
                    size_t off = (((size_t)b * NH + hh) * SEQ + s) * HD + dd;
                    qkv[(size_t)wsel * WSZ + off] = f2bf(acc[mi][ni][r] * sc);
                }
    }
}

// ---------------------------------------------------------------------------
// Kernel 2: flash attention — round-5 structure (best measured: 173 us).
// 4 waves x 32 q; K/V^T staged via global_load_lds + XOR swizzle; fixed-max
// softmax in log2 domain (Q pre-scaled C2, mask pre-scaled LOG2E as bf16).
// Orthogonal wins kept from r8: bf16 mask read direct from global (no Msm),
// HW pkbf16 pack, hoisted zero C-operand.
// ---------------------------------------------------------------------------
__global__ __launch_bounds__(256) void flash_attn(
    const unsigned short* __restrict__ qkv,
    const unsigned short* __restrict__ maskB,   // bf16(LOG2E*mask) [b][key]
    unsigned short* __restrict__ ctx) {
    __shared__ __align__(16) unsigned short Ksm[64 * 64];   // [key][dim], swizzled
    __shared__ __align__(16) unsigned short Vtsm[64 * 64];  // [dim][key], swizzled
    __shared__ __align__(16) unsigned short Psm[4][32][72]; // per-wave [q][key]
    const int t  = threadIdx.x;
    const int bh = blockIdx.y;
    const int b  = bh / NH;
    const int h  = bh % NH;
    const int qbase = blockIdx.x * 128;
    const size_t WSZ = (size_t)BHT * SEQ * HD;
    const unsigned short* Qp = qkv + (size_t)bh * SEQ * HD;
    const unsigned short* Kp = Qp + WSZ;
    const unsigned short* Vt = qkv + 2 * WSZ + (size_t)bh * HD * SEQ; // [d][s]
    const unsigned short* mrow = maskB + b * SEQ;
    const int w = t >> 6, lane = t & 63, n31 = lane & 31, hi = lane >> 5;
    const int lrow = lane >> 3;
    const int lchs = ((lane & 7) ^ (lrow & 7)) * 8;
    const int sw = n31 & 7;

    bf16x8 qF[4];
    {
        int qrow = qbase + w * 32 + n31;
#pragma unroll
        for (int kc = 0; kc < 4; ++kc)
            qF[kc] = *(const bf16x8*)&Qp[(size_t)qrow * HD + kc * 16 + hi * 8];
    }
    bf16x8 bOnes = {};
    if (hi == 0) bOnes[0] = (short)0x3F80;   // 1.0 at k==0 (mask broadcast)
    const f32x16 kZero = {};

    f32x16 oAcc[2] = {};
    float l_i = 0.0f;

    for (int kt = 0; kt < SEQ / 64; ++kt) {
#pragma unroll
        for (int i = 0; i < 2; ++i) {
            int row = w * 16 + i * 8;
            cp16(&Kp[(size_t)(kt * 64 + row + lrow) * HD + lchs], &Ksm[row * 64]);
            cp16(&Vt[(size_t)(row + lrow) * SEQ + kt * 64 + lchs], &Vtsm[row * 64]);
        }
        __syncthreads();

        // S^T = K Q^T (log2 domain) + mask via MFMA C-init; exp2; pack -> Psm
#pragma unroll
        for (int st = 0; st < 2; ++st) {
            bf16x8 am = {};
            {
                unsigned short mv = mrow[kt * 64 + st * 32 + n31];
                am[0] = (hi == 0) ? (short)mv : (short)0;
            }
            f32x16 sA = __builtin_amdgcn_mfma_f32_32x32x16_bf16(am, bOnes, kZero, 0, 0, 0);
#pragma unroll
            for (int kc = 0; kc < 4; ++kc) {
                bf16x8 kF = *(const bf16x8*)
                    &Ksm[(st * 32 + n31) * 64 + (((2 * kc + hi) ^ sw) * 8)];
                sA = __builtin_amdgcn_mfma_f32_32x32x16_bf16(kF, qF[kc], sA, 0, 0, 0);
            }
            float r0 = 0.f, r1 = 0.f, r2 = 0.f, r3 = 0.f;
#pragma unroll
            for (int g = 0; g < 4; ++g) {
                float p0 = __builtin_amdgcn_exp2f(sA[4 * g + 0]);
                float p1 = __builtin_amdgcn_exp2f(sA[4 * g + 1]);
                float p2 = __builtin_amdgcn_exp2f(sA[4 * g + 2]);
                float p3 = __builtin_amdgcn_exp2f(sA[4 * g + 3]);
                r0 += p0; r1 += p1; r2 += p2; r3 += p3;
                uint2 dd;
                dd.x = pkbf16(p0, p1);
                dd.y = pkbf16(p2, p3);
                *(uint2*)&Psm[w][n31][st * 32 + hi * 4 + 8 * g] = dd;
            }
            l_i += (r0 + r1) + (r2 + r3);
        }

        // O^T += V^T P^T
#pragma unroll
        for (int kc = 0; kc < 4; ++kc) {
            bf16x8 pF = *(const bf16x8*)&Psm[w][n31][kc * 16 + hi * 8];
#pragma unroll
            for (int dt = 0; dt < 2; ++dt) {
                bf16x8 vF = *(const bf16x8*)
                    &Vtsm[(dt * 32 + n31) * 64 + (((2 * kc + hi) ^ sw) * 8)];
                oAcc[dt] = __builtin_amdgcn_mfma_f32_32x32x16_bf16(vF, pF, oAcc[dt], 0, 0, 0);
            }
        }
        __syncthreads();
    }
    // epilogue: lane covers half the keys; partner (lane^32) has the other half
    l_i += __shfl_xor(l_i, 32);
    float inv = 1.0f / l_i;
    int s = qbase + w * 32 + n31;
    unsigned short* obase = &ctx[((size_t)b * SEQ + s) * ED + h * HD];
#pragma unroll
    for (int dt = 0; dt < 2; ++dt)
#pragma unroll
        for (int g = 0; g < 4; ++g) {
            uint2 o;
            o.x = pkbf16(oAcc[dt][4 * g + 0] * inv, oAcc[dt][4 * g + 1] * inv);
            o.y = pkbf16(oAcc[dt][4 * g + 2] * inv, oAcc[dt][4 * g + 3] * inv);
            *(uint2*)&obase[dt * 32 + hi * 4 + 8 * g] = o;
        }
}

// ---------------------------------------------------------------------------
// Kernel 3: output projection, 128x128 tile.
// ---------------------------------------------------------------------------
__global__ __launch_bounds__(256) void out_gemm(
    const unsigned short* __restrict__ Ab,   // ctx bf16 [8192][768]
    const unsigned short* __restrict__ Wob,  // [768][768] bf16
    const float* __restrict__ bo, float* __restrict__ out) {
    __shared__ __align__(16) unsigned short Ah[128 * 64];
    __shared__ __align__(16) unsigned short Bh[128 * 64];
    const int t = threadIdx.x, w = t >> 6, lane = t & 63;
    const int quad = lane >> 4, r16 = lane & 15;
    const int wm = w >> 1, wn = w & 1;
    const int m0 = blockIdx.y * 128, n0 = blockIdx.x * 128;
    const int lrow = lane >> 3;
    const int lchs = ((lane & 7) ^ (lrow & 7)) * 8;

    f32x4 acc[4][4] = {};
    for (int kt = 0; kt < ED / 64; ++kt) {
        const int k0 = kt * 64;
#pragma unroll
        for (int i = 0; i < 4; ++i) {
            int row = i * 32 + w * 8;
            cp16(&Ab[(size_t)(m0 + row + lrow) * ED + k0 + lchs], &Ah[row * 64]);
            cp16(&Wob[(size_t)(n0 + row + lrow) * ED + k0 + lchs], &Bh[row * 64]);
        }
        __syncthreads();
#pragma unroll
        for (int kk = 0; kk < 2; ++kk) {
            bf16x8 aF[4], bF[4];
#pragma unroll
            for (int mi = 0; mi < 4; ++mi) {
                int R = wm * 64 + mi * 16 + r16;
                aF[mi] = *(const bf16x8*)&Ah[R * 64 + (((kk * 4 + quad) ^ (r16 & 7)) * 8)];
            }
#pragma unroll
            for (int ni = 0; ni < 4; ++ni) {
                int R = wn * 64 + ni * 16 + r16;
                bF[ni] = *(const bf16x8*)&Bh[R * 64 + (((kk * 4 + quad) ^ (r16 & 7)) * 8)];
            }
#pragma unroll
            for (int mi = 0; mi < 4; ++mi)
#pragma unroll
                for (int ni = 0; ni < 4; ++ni)
                    acc[mi][ni] = __builtin_amdgcn_mfma_f32_16x16x32_bf16(
                        aF[mi], bF[ni], acc[mi][ni], 0, 0, 0);
        }
        __syncthreads();
    }
    float bov[4];
#pragma unroll
    for (int ni = 0; ni < 4; ++ni) bov[ni] = bo[n0 + wn * 64 + ni * 16 + r16];
#pragma unroll
    for (int mi = 0; mi < 4; ++mi)
#pragma unroll
        for (int ni = 0; ni < 4; ++ni)
#pragma unroll
            for (int r = 0; r < 4; ++r) {
                int m = m0 + wm * 64 + mi * 16 + quad * 4 + r;
                int n = n0 + wn * 64 + ni * 16 + r16;
                out[(size_t)m * ED + n] = acc[mi][ni][r] + bov[ni];
            }
}

// ---------------------------------------------------------------------------
extern "C" void kernel_launch(void* const* d_in, const int* in_sizes, int n_in,
                              void* d_out, int out_size, void* d_ws, size_t ws_size,
                              hipStream_t stream) {
    const float* H    = (const float*)d_in[0];
    const float* mask = (const float*)d_in[1];
    const float* Wq   = (const float*)d_in[2];
    const float* Wk   = (const float*)d_in[3];
    const float* Wv   = (const float*)d_in[4];
    const float* Wo   = (const float*)d_in[5];
    const float* bo   = (const float*)d_in[6];
    unsigned short* ws = (unsigned short*)d_ws;
    const size_t WSZ = (size_t)BHT * SEQ * HD;
    unsigned short* qkv   = ws;                           // 3*WSZ bf16
    unsigned short* ctx   = ws + 3 * WSZ;                 // [8192][768] bf16
    unsigned short* WoB   = ctx + (size_t)MTOT * ED;      // [768][768] bf16
    unsigned short* maskB = WoB + (size_t)ED * ED;        // [2][4096] bf16
    float* out = (float*)d_out;
    unsigned short* Hb = (unsigned short*)d_out;          // scratch until out_gemm
    unsigned short* Wb = Hb + (size_t)MTOT * ED;

    convert_bf16<<<CVT_TOTAL / 256, 256, 0, stream>>>(H, Wq, Wk, Wv, Wo, mask,
                                                      Hb, WoB, maskB);
    qkv_gemm<<<dim3(3 * ED / 128, MTOT / 128), 256, 0, stream>>>(Hb, Wb, qkv);
    flash_attn<<<dim3(SEQ / 128, BHT), 256, 0, stream>>>(qkv, maskB, ctx);
    out_gemm<<<dim3(ED / 128, MTOT / 128), 256, 0, stream>>>(ctx, WoB, bo, out);
}